// Round 2
// baseline (68.998 us; speedup 1.0000x reference)
//
#include <hip/hip_runtime.h>
#include <math.h>

// KANLinear forward, MI355X.
// out[b,i,o] = silu( (x@W)[b,o] + sum_k basis[b,i,k] * sw[i,o,k] )
// b=1024, i=256, o=256, k=7. Output 268MB f32 -> write-bound (~40us floor @ ~7TB/s).

#define NF 256
#define BCH 8   // batch rows per block
#define ICH 16  // input features per block

typedef float f32x4 __attribute__((ext_vector_type(4)));

__device__ __forceinline__ float silu_f(float z) {
    float e = __expf(-z);
    return z * __builtin_amdgcn_rcpf(1.0f + e);
}

// ---------------- Kernel 1: base = x @ W  (1024x256 @ 256x256) ----------------
__global__ __launch_bounds__(256) void base_gemm(const float* __restrict__ x,
                                                 const float* __restrict__ W,
                                                 float* __restrict__ base) {
    __shared__ float xs[2][NF];
    const int b0 = blockIdx.x * 2;
    const int t = threadIdx.x;
    xs[0][t] = x[(b0 + 0) * NF + t];
    xs[1][t] = x[(b0 + 1) * NF + t];
    __syncthreads();
    float acc0 = 0.f, acc1 = 0.f;
#pragma unroll 8
    for (int k = 0; k < NF; ++k) {
        float w = W[k * NF + t];
        acc0 += xs[0][k] * w;
        acc1 += xs[1][k] * w;
    }
    base[(b0 + 0) * NF + t] = acc0;
    base[(b0 + 1) * NF + t] = acc1;
}

// ---------------- Kernel 2: fused basis + spline einsum + silu ----------------
// grid: (16 i-chunks, 128 b-chunks); 256 threads. Per block: 8 b-rows x 16 i-feats.
__global__ __launch_bounds__(256) void kan_main(const float* __restrict__ x,
                                                const float* __restrict__ sw,
                                                const float* __restrict__ grid,
                                                const float* __restrict__ base,
                                                float* __restrict__ out) {
    const int i0 = blockIdx.x * ICH;
    const int b0 = blockIdx.y * BCH;
    const int tid = threadIdx.x;

    __shared__ float bas[ICH][BCH][8];   // 4 KB  [ii][bb][k]
    __shared__ float base_s[BCH][NF];    // 8 KB

    // ---- cooperative load of base rows (512 float4 over 256 threads) ----
#pragma unroll
    for (int r = 0; r < 2; ++r) {
        const int f4 = tid + r * 256;        // float4 index 0..511
        const int row = f4 >> 6;             // 64 float4 per row
        const int c4 = (f4 & 63) * 4;
        *reinterpret_cast<f32x4*>(&base_s[row][c4]) =
            *reinterpret_cast<const f32x4*>(&base[(size_t)(b0 + row) * NF + c4]);
    }

    // ---- Phase A: threads 0..127 compute the 7-basis for one (bb, ii) pair ----
    if (tid < ICH * BCH) {
        const int ii = tid & (ICH - 1);
        const int bb = tid >> 4;
        const int gi = i0 + ii;
        const float xv = x[(size_t)(b0 + bb) * NF + gi];
        const float g0 = grid[0 * NF + gi];
        const float g1 = grid[1 * NF + gi];
        const float g2 = grid[2 * NF + gi];
        const float g3 = grid[3 * NF + gi];
        const float g4 = grid[4 * NF + gi];
        const float L = 2.f * g0 - g3;
        const float R = 2.f * g4 - g1;
        float eg[11] = {L, L, L, g0, g1, g2, g3, g4, R, R, R};

        float B0[10];
#pragma unroll
        for (int t = 0; t < 10; ++t)
            B0[t] = (xv >= eg[t] && xv < eg[t + 1]) ? 1.f : 0.f;
        float B1[9];
#pragma unroll
        for (int t = 0; t < 9; ++t) {
            float dl = eg[t + 1] - eg[t];
            float dr = eg[t + 2] - eg[t + 1];
            float lt = (dl != 0.f) ? (xv - eg[t]) / dl : 0.f;
            float rt = (dr != 0.f) ? (eg[t + 2] - xv) / dr : 0.f;
            B1[t] = lt * B0[t] + rt * B0[t + 1];
        }
        float B2[8];
#pragma unroll
        for (int t = 0; t < 8; ++t) {
            float dl = eg[t + 2] - eg[t];
            float dr = eg[t + 3] - eg[t + 1];
            float lt = (dl != 0.f) ? (xv - eg[t]) / dl : 0.f;
            float rt = (dr != 0.f) ? (eg[t + 3] - xv) / dr : 0.f;
            B2[t] = lt * B1[t] + rt * B1[t + 1];
        }
#pragma unroll
        for (int k = 0; k < 7; ++k) bas[ii][bb][k] = B2[k];
        bas[ii][bb][7] = 0.f;
    }

    __syncthreads();

    const int lane = tid & 63;
    const int wv = tid >> 6; // wave 0..3, owns ii = wv*4 + step

    for (int step = 0; step < 4; ++step) {
        const int ii = wv * 4 + step;
        const int i = i0 + ii;

        // sw fragment: 28 contiguous floats per lane = 7 x dwordx4
        f32x4 q[7];
        const f32x4* p4 = reinterpret_cast<const f32x4*>(
            &sw[((size_t)i * NF + lane * 4) * 7]);
#pragma unroll
        for (int j = 0; j < 7; ++j) q[j] = p4[j];
        float s[28];
#pragma unroll
        for (int j = 0; j < 7; ++j) {
            s[j * 4 + 0] = q[j].x; s[j * 4 + 1] = q[j].y;
            s[j * 4 + 2] = q[j].z; s[j * 4 + 3] = q[j].w;
        }

        float* op = out + ((size_t)b0 * NF + i) * NF + lane * 4;

#pragma unroll
        for (int bb = 0; bb < BCH; ++bb) {
            f32x4 bl = *reinterpret_cast<const f32x4*>(&bas[ii][bb][0]);
            f32x4 bh = *reinterpret_cast<const f32x4*>(&bas[ii][bb][4]);
            const float bk[7] = {bl.x, bl.y, bl.z, bl.w, bh.x, bh.y, bh.z};
            f32x4 bs = *reinterpret_cast<const f32x4*>(&base_s[bb][lane * 4]);
            float a0 = bs.x, a1 = bs.y, a2 = bs.z, a3 = bs.w;
#pragma unroll
            for (int k = 0; k < 7; ++k) {
                a0 += bk[k] * s[0 * 7 + k];
                a1 += bk[k] * s[1 * 7 + k];
                a2 += bk[k] * s[2 * 7 + k];
                a3 += bk[k] * s[3 * 7 + k];
            }
            f32x4 o4;
            o4.x = silu_f(a0);
            o4.y = silu_f(a1);
            o4.z = silu_f(a2);
            o4.w = silu_f(a3);
            __builtin_nontemporal_store(o4,
                reinterpret_cast<f32x4*>(op + (size_t)bb * NF * NF));
        }
    }
}

extern "C" void kernel_launch(void* const* d_in, const int* in_sizes, int n_in,
                              void* d_out, int out_size, void* d_ws, size_t ws_size,
                              hipStream_t stream) {
    const float* x    = (const float*)d_in[0]; // (1024, 256)
    const float* bw   = (const float*)d_in[1]; // (256, 256)
    const float* sw   = (const float*)d_in[2]; // (256, 256, 7)
    const float* grid = (const float*)d_in[3]; // (5, 256)
    float* out = (float*)d_out;                // (1024, 256, 256)
    float* base = (float*)d_ws;                // 1 MB scratch for x@W

    base_gemm<<<dim3(512), 256, 0, stream>>>(x, bw, base);
    kan_main<<<dim3(16, 128), 256, 0, stream>>>(x, sw, grid, base, out);
}

// Round 4
// 65.225 us; speedup vs baseline: 1.0578x; 1.0578x over previous
//
#include <hip/hip_runtime.h>
#include <math.h>

// KANLinear forward, MI355X.
// out[b,i,o] = silu( (x@W)[b,o] + sum_k basis[b,i,k] * sw[i,o,k] )
// b=1024, i=256, o=256, k=7. Output 268MB f32 -> write-bound (~39us floor @ 6.9TB/s fill rate).

#define NF 256
#define BCH 16  // batch rows per block
#define ICH 16  // input features per block

typedef float f32x4 __attribute__((ext_vector_type(4)));

__device__ __forceinline__ float silu_f(float z) {
    float e = __expf(-z);
    return z * __builtin_amdgcn_rcpf(1.0f + e);
}

// ---------------- Kernel 1: base = x @ W  (1024x256 @ 256x256) ----------------
// 4 rows/block, 256 blocks: W re-read 256x = 67MB L2 traffic.
__global__ __launch_bounds__(256) void base_gemm(const float* __restrict__ x,
                                                 const float* __restrict__ W,
                                                 float* __restrict__ base) {
    __shared__ float xs[4][NF];
    const int b0 = blockIdx.x * 4;
    const int t = threadIdx.x;
    {
        const int row = t >> 6;
        const int c4 = (t & 63) * 4;
        *reinterpret_cast<f32x4*>(&xs[row][c4]) =
            *reinterpret_cast<const f32x4*>(&x[(size_t)(b0 + row) * NF + c4]);
    }
    __syncthreads();
    float acc0 = 0.f, acc1 = 0.f, acc2 = 0.f, acc3 = 0.f;
#pragma unroll 8
    for (int k = 0; k < NF; ++k) {
        float w = W[k * NF + t];
        acc0 += xs[0][k] * w;
        acc1 += xs[1][k] * w;
        acc2 += xs[2][k] * w;
        acc3 += xs[3][k] * w;
    }
    base[(size_t)(b0 + 0) * NF + t] = acc0;
    base[(size_t)(b0 + 1) * NF + t] = acc1;
    base[(size_t)(b0 + 2) * NF + t] = acc2;
    base[(size_t)(b0 + 3) * NF + t] = acc3;
}

// ---------------- Kernel 2: fused basis + spline einsum + silu ----------------
// grid: (16 i-chunks, 64 b-chunks); 256 threads. Per block: 16 b-rows x 16 i-feats.
__global__ __launch_bounds__(256) void kan_main(const float* __restrict__ x,
                                                const float* __restrict__ sw,
                                                const float* __restrict__ grid,
                                                const float* __restrict__ base,
                                                float* __restrict__ out) {
    const int i0 = blockIdx.x * ICH;
    const int b0 = blockIdx.y * BCH;
    const int tid = threadIdx.x;

    __shared__ float bas[ICH][BCH][8];   // 8 KB  [ii][bb][k]
    __shared__ float base_s[BCH][NF];    // 16 KB

    // ---- cooperative load of base rows (1024 float4 over 256 threads) ----
#pragma unroll
    for (int r = 0; r < 4; ++r) {
        const int f4 = tid + r * 256;        // float4 index 0..1023
        const int row = f4 >> 6;             // 64 float4 per row
        const int c4 = (f4 & 63) * 4;
        *reinterpret_cast<f32x4*>(&base_s[row][c4]) =
            *reinterpret_cast<const f32x4*>(&base[(size_t)(b0 + row) * NF + c4]);
    }

    // ---- Phase A: each thread computes the 7-basis for one (bb, ii) pair ----
    {
        const int ii = tid & (ICH - 1);
        const int bb = tid >> 4;
        const int gi = i0 + ii;
        const float xv = x[(size_t)(b0 + bb) * NF + gi];
        const float g0 = grid[0 * NF + gi];
        const float g1 = grid[1 * NF + gi];
        const float g2 = grid[2 * NF + gi];
        const float g3 = grid[3 * NF + gi];
        const float g4 = grid[4 * NF + gi];
        const float L = 2.f * g0 - g3;
        const float R = 2.f * g4 - g1;
        float eg[11] = {L, L, L, g0, g1, g2, g3, g4, R, R, R};

        float B0[10];
#pragma unroll
        for (int t = 0; t < 10; ++t)
            B0[t] = (xv >= eg[t] && xv < eg[t + 1]) ? 1.f : 0.f;
        float B1[9];
#pragma unroll
        for (int t = 0; t < 9; ++t) {
            float dl = eg[t + 1] - eg[t];
            float dr = eg[t + 2] - eg[t + 1];
            float lt = (dl != 0.f) ? (xv - eg[t]) / dl : 0.f;
            float rt = (dr != 0.f) ? (eg[t + 2] - xv) / dr : 0.f;
            B1[t] = lt * B0[t] + rt * B0[t + 1];
        }
        float B2[8];
#pragma unroll
        for (int t = 0; t < 8; ++t) {
            float dl = eg[t + 2] - eg[t];
            float dr = eg[t + 3] - eg[t + 1];
            float lt = (dl != 0.f) ? (xv - eg[t]) / dl : 0.f;
            float rt = (dr != 0.f) ? (eg[t + 3] - xv) / dr : 0.f;
            B2[t] = lt * B1[t] + rt * B1[t + 1];
        }
#pragma unroll
        for (int k = 0; k < 7; ++k) bas[ii][bb][k] = B2[k];
        bas[ii][bb][7] = 0.f;
    }

    __syncthreads();

    const int lane = tid & 63;
    const int wv = tid >> 6;

    for (int step = 0; step < 4; ++step) {
        // interleaved: the 4 waves cover 4 consecutive i rows each step
        const int ii = step * 4 + wv;
        const int i = i0 + ii;

        // sw fragment: 28 contiguous floats per lane = 7 x dwordx4,
        // layout flat[oo*7 + k] -> repack into s[] (compile-time, reg renaming)
        f32x4 q[7];
        const f32x4* p4 = reinterpret_cast<const f32x4*>(
            &sw[((size_t)i * NF + lane * 4) * 7]);
#pragma unroll
        for (int j = 0; j < 7; ++j) q[j] = p4[j];
        float s[28];
#pragma unroll
        for (int j = 0; j < 7; ++j) {
            s[j * 4 + 0] = q[j].x; s[j * 4 + 1] = q[j].y;
            s[j * 4 + 2] = q[j].z; s[j * 4 + 3] = q[j].w;
        }

        float* op = out + ((size_t)b0 * NF + i) * NF + lane * 4;

#pragma unroll
        for (int bb = 0; bb < BCH; ++bb) {
            f32x4 bl = *reinterpret_cast<const f32x4*>(&bas[ii][bb][0]);
            f32x4 bh = *reinterpret_cast<const f32x4*>(&bas[ii][bb][4]);
            const float bk[7] = {bl.x, bl.y, bl.z, bl.w, bh.x, bh.y, bh.z};
            f32x4 bs = *reinterpret_cast<const f32x4*>(&base_s[bb][lane * 4]);
            float a0 = bs.x, a1 = bs.y, a2 = bs.z, a3 = bs.w;
#pragma unroll
            for (int k = 0; k < 7; ++k) {
                a0 += bk[k] * s[0 * 7 + k];
                a1 += bk[k] * s[1 * 7 + k];
                a2 += bk[k] * s[2 * 7 + k];
                a3 += bk[k] * s[3 * 7 + k];
            }
            f32x4 o4;
            o4.x = silu_f(a0);
            o4.y = silu_f(a1);
            o4.z = silu_f(a2);
            o4.w = silu_f(a3);
            *reinterpret_cast<f32x4*>(op + (size_t)bb * NF * NF) = o4;
        }
    }
}

extern "C" void kernel_launch(void* const* d_in, const int* in_sizes, int n_in,
                              void* d_out, int out_size, void* d_ws, size_t ws_size,
                              hipStream_t stream) {
    const float* x    = (const float*)d_in[0]; // (1024, 256)
    const float* bw   = (const float*)d_in[1]; // (256, 256)
    const float* sw   = (const float*)d_in[2]; // (256, 256, 7)
    const float* grid = (const float*)d_in[3]; // (5, 256)
    float* out = (float*)d_out;                // (1024, 256, 256)
    float* base = (float*)d_ws;                // 1 MB scratch for x@W

    base_gemm<<<dim3(256), 256, 0, stream>>>(x, bw, base);
    kan_main<<<dim3(16, 64), 256, 0, stream>>>(x, sw, grid, base, out);
}